// Round 1
// baseline (30.625 us; speedup 1.0000x reference)
//
#include <hip/hip_runtime.h>
#include <cmath>

// Bokeh render (scatter form in ref == this gather form):
// out[b,c,y,x] = sum_{dy,dx in [-4,4]} w * img[b,c,y-dy,x-dx] / sum w
// w = sigmoid(8*(r_src - dist)) * 1/max(pi*r_src^2,1),
//     masked by max(|dy|,|dx|) <= floor(r_src)+1 and src in-bounds.
// r = |defocus| in [0,4) so floor(r)+1 <= 4 -> 9x9 window suffices
// (the reference's R=5 ring is always masked out).

#define HH 512
#define WW 512
#define NB 2
#define TILE 32
#define HALO 4
#define SROWS (TILE + 2 * HALO)   // 40
#define LW 44                     // LDS row stride (16B-aligned, conflict-free)

struct BokehConsts {
  float fd2[33];  // exp(8*sqrt(d2)) for d2 = dy^2+dx^2 in [0,32]
  float thr[5];   // exp(-8*(m-1)) for m = max(|dy|,|dx|) in [0,4]
};

__global__ __launch_bounds__(256) void bokeh_gather(
    const float* __restrict__ img,
    const float* __restrict__ def,
    float* __restrict__ out,
    BokehConsts cst)
{
  __shared__ __align__(16) float sG[SROWS][LW];
  __shared__ __align__(16) float sIv[SROWS][LW];
  __shared__ __align__(16) float sI0[SROWS][LW];
  __shared__ __align__(16) float sI1[SROWS][LW];
  __shared__ __align__(16) float sI2[SROWS][LW];

  const int tid = threadIdx.x;
  const int tx = tid & 7;        // 8 threads * 4 px = 32 cols
  const int ty = tid >> 3;       // 32 rows
  const int bx = blockIdx.x * TILE;
  const int by = blockIdx.y * TILE;
  const int b  = blockIdx.z;

  const float* dpt = def + b * (HH * WW);
  const float* ipt = img + b * (3 * HH * WW);

  // Stage halo'd source tile: G = exp(-8r), inv = 1/max(pi r^2,1), 3 channels.
  // OOB sources -> all zeros => weight exactly 0 (matches ref's src_val mask).
  for (int idx = tid; idx < SROWS * SROWS; idx += 256) {
    int ly = idx / SROWS;
    int lx = idx - ly * SROWS;
    int sy = by - HALO + ly;
    int sx = bx - HALO + lx;
    float G = 0.f, iv = 0.f, a0 = 0.f, a1 = 0.f, a2 = 0.f;
    if (sy >= 0 && sy < HH && sx >= 0 && sx < WW) {
      int o = sy * WW + sx;
      float r = fabsf(dpt[o]);
      G  = __expf(-8.0f * r);
      iv = 1.0f / fmaxf(3.14159265358979f * r * r, 1.0f);
      a0 = ipt[o];
      a1 = ipt[o + HH * WW];
      a2 = ipt[o + 2 * HH * WW];
    }
    sG[ly][lx]  = G;
    sIv[ly][lx] = iv;
    sI0[ly][lx] = a0;
    sI1[ly][lx] = a1;
    sI2[ly][lx] = a2;
  }
  __syncthreads();

  float wsum[4] = {0.f, 0.f, 0.f, 0.f};
  float ac0[4]  = {0.f, 0.f, 0.f, 0.f};
  float ac1[4]  = {0.f, 0.f, 0.f, 0.f};
  float ac2[4]  = {0.f, 0.f, 0.f, 0.f};

  const int col0 = 4 * tx;  // LDS col of source-window start (16B aligned)

  #pragma unroll
  for (int dy = 0; dy < 9; ++dy) {
    const int dyo = dy - 4;
    const int ady = dyo < 0 ? -dyo : dyo;
    const int dy2 = dyo * dyo;
    const int sr = ty + dy;
    const float* rG = &sG[sr][col0];
    const float* rI = &sIv[sr][col0];
    const float* r0 = &sI0[sr][col0];
    const float* r1 = &sI1[sr][col0];
    const float* r2 = &sI2[sr][col0];
    float Gv[12], Iv[12], P0[12], P1[12], P2[12];
    #pragma unroll
    for (int q = 0; q < 3; ++q) {
      *(float4*)&Gv[4 * q] = *(const float4*)(rG + 4 * q);
      *(float4*)&Iv[4 * q] = *(const float4*)(rI + 4 * q);
      *(float4*)&P0[4 * q] = *(const float4*)(r0 + 4 * q);
      *(float4*)&P1[4 * q] = *(const float4*)(r1 + 4 * q);
      *(float4*)&P2[4 * q] = *(const float4*)(r2 + 4 * q);
    }
    #pragma unroll
    for (int k = 0; k < 4; ++k) {
      #pragma unroll
      for (int j = k; j < k + 9; ++j) {
        const int dxo = j - 4 - k;               // compile-time
        const int adx = dxo < 0 ? -dxo : dxo;
        const int m   = adx > ady ? adx : ady;
        const int d2  = dy2 + dxo * dxo;
        const float Fd = cst.fd2[d2];            // exp(8*dist)
        const float th = cst.thr[m];             // exp(-8*(m-1))
        float g = Gv[j];
        float t = fmaf(g, Fd, 1.0f);             // 1 + e^{-8r} e^{8d}
        float w = __builtin_amdgcn_rcpf(t) * Iv[j];
        w = (g <= th) ? w : 0.0f;                // window mask (r >= m-1)
        wsum[k] += w;
        ac0[k] = fmaf(w, P0[j], ac0[k]);
        ac1[k] = fmaf(w, P1[j], ac1[k]);
        ac2[k] = fmaf(w, P2[j], ac2[k]);
      }
    }
  }

  const int oy = by + ty;
  const int ox = bx + col0;
  float rw[4];
  #pragma unroll
  for (int k = 0; k < 4; ++k) rw[k] = __builtin_amdgcn_rcpf(wsum[k]);

  float* op0 = out + ((b * 3 + 0) * HH + oy) * WW + ox;
  float* op1 = out + ((b * 3 + 1) * HH + oy) * WW + ox;
  float* op2 = out + ((b * 3 + 2) * HH + oy) * WW + ox;
  float4 v0, v1, v2;
  v0.x = ac0[0] * rw[0]; v0.y = ac0[1] * rw[1]; v0.z = ac0[2] * rw[2]; v0.w = ac0[3] * rw[3];
  v1.x = ac1[0] * rw[0]; v1.y = ac1[1] * rw[1]; v1.z = ac1[2] * rw[2]; v1.w = ac1[3] * rw[3];
  v2.x = ac2[0] * rw[0]; v2.y = ac2[1] * rw[1]; v2.z = ac2[2] * rw[2]; v2.w = ac2[3] * rw[3];
  *(float4*)op0 = v0;
  *(float4*)op1 = v1;
  *(float4*)op2 = v2;
}

extern "C" void kernel_launch(void* const* d_in, const int* in_sizes, int n_in,
                              void* d_out, int out_size, void* d_ws, size_t ws_size,
                              hipStream_t stream) {
  const float* img = (const float*)d_in[0];   // (2,3,512,512) f32
  const float* def = (const float*)d_in[1];   // (2,1,512,512) f32
  float* out = (float*)d_out;                 // (2,3,512,512) f32

  BokehConsts cst;
  for (int s = 0; s <= 32; ++s) cst.fd2[s] = expf(8.0f * sqrtf((float)s));
  for (int m = 0; m < 5; ++m)   cst.thr[m] = expf(-8.0f * (float)(m - 1));

  dim3 grid(WW / TILE, HH / TILE, NB);
  dim3 block(256);
  hipLaunchKernelGGL(bokeh_gather, grid, block, 0, stream, img, def, out, cst);
}

// Round 2
// 26.863 us; speedup vs baseline: 1.1400x; 1.1400x over previous
//
#include <hip/hip_runtime.h>
#include <cmath>

// Bokeh render (scatter form in ref == this gather form):
// out[b,c,y,x] = sum_{dy,dx in [-4,4]} w * img[b,c,y-dy,x-dx] / sum w
// w = sigmoid(8*(r_src - dist)) * 1/max(pi*r_src^2,1),
//     masked by max(|dy|,|dx|) <= floor(r_src)+1 and src in-bounds.
// r = |defocus| in [0,4) so floor(r)+1 <= 4 -> 9x9 window suffices.
//
// R1 lesson: full 9x unroll of the dy loop hoisted 45 ds_read_b128 (540 live
// floats) -> VGPR spill -> ~30us. This version pins the dy loop to unroll 1
// (live set ~1 row) and moves the per-(dy,dx) constants exp(8*dist) and
// exp(-8*(m-1)) into small LDS tables read via wave-uniform broadcasts.

#define HH 512
#define WW 512
#define NB 2
#define TILE 32
#define HALO 4
#define SROWS (TILE + 2 * HALO)   // 40
#define LW 44                     // LDS row stride (16B-aligned, conflict-free)

__global__ __launch_bounds__(256, 2) void bokeh_gather(
    const float* __restrict__ img,
    const float* __restrict__ def,
    float* __restrict__ out)
{
  __shared__ __align__(16) float sG[SROWS][LW];
  __shared__ __align__(16) float sIv[SROWS][LW];
  __shared__ __align__(16) float sI0[SROWS][LW];
  __shared__ __align__(16) float sI1[SROWS][LW];
  __shared__ __align__(16) float sI2[SROWS][LW];
  __shared__ float sFd[9][12];  // exp(8*dist) per (dy,dx)
  __shared__ float sTh[9][12];  // exp(-8*(m-1)) per (dy,dx), m = max(|dy|,|dx|)

  const int tid = threadIdx.x;
  const int tx = tid & 7;        // 8 threads * 4 px = 32 cols
  const int ty = tid >> 3;       // 32 rows
  const int bx = blockIdx.x * TILE;
  const int by = blockIdx.y * TILE;
  const int b  = blockIdx.z;

  // Per-offset constant tables (computed once per block; cheap).
  if (tid < 81) {
    int dyi = tid / 9, dxi = tid - dyi * 9;
    int dyo = dyi - 4, dxo = dxi - 4;
    int ady = dyo < 0 ? -dyo : dyo;
    int adx = dxo < 0 ? -dxo : dxo;
    int m = ady > adx ? ady : adx;
    float d2 = (float)(dyo * dyo + dxo * dxo);
    sFd[dyi][dxi] = __expf(8.0f * sqrtf(d2));
    sTh[dyi][dxi] = __expf(-8.0f * (float)(m - 1));
  }

  const float* dpt = def + b * (HH * WW);
  const float* ipt = img + b * (3 * HH * WW);

  // Stage halo'd source tile: G = exp(-8r), inv = 1/max(pi r^2,1), 3 channels.
  // OOB sources -> all zeros => weight exactly 0 (matches ref's src_val mask).
  for (int idx = tid; idx < SROWS * SROWS; idx += 256) {
    int ly = idx / SROWS;
    int lx = idx - ly * SROWS;
    int sy = by - HALO + ly;
    int sx = bx - HALO + lx;
    float G = 0.f, iv = 0.f, a0 = 0.f, a1 = 0.f, a2 = 0.f;
    if (sy >= 0 && sy < HH && sx >= 0 && sx < WW) {
      int o = sy * WW + sx;
      float r = fabsf(dpt[o]);
      G  = __expf(-8.0f * r);
      iv = __builtin_amdgcn_rcpf(fmaxf(3.14159265358979f * r * r, 1.0f));
      a0 = ipt[o];
      a1 = ipt[o + HH * WW];
      a2 = ipt[o + 2 * HH * WW];
    }
    sG[ly][lx]  = G;
    sIv[ly][lx] = iv;
    sI0[ly][lx] = a0;
    sI1[ly][lx] = a1;
    sI2[ly][lx] = a2;
  }
  __syncthreads();

  float wsum[4] = {0.f, 0.f, 0.f, 0.f};
  float ac0[4]  = {0.f, 0.f, 0.f, 0.f};
  float ac1[4]  = {0.f, 0.f, 0.f, 0.f};
  float ac2[4]  = {0.f, 0.f, 0.f, 0.f};

  const int col0 = 4 * tx;  // LDS col of source-window start (16B aligned)

  #pragma unroll 1
  for (int dy = 0; dy < 9; ++dy) {
    const int sr = ty + dy;
    // Per-row offset constants (wave-uniform LDS broadcasts -> 18 VGPRs).
    float fdr[9], thv[9];
    #pragma unroll
    for (int x = 0; x < 9; ++x) { fdr[x] = sFd[dy][x]; thv[x] = sTh[dy][x]; }

    const float* rG = &sG[sr][col0];
    const float* rI = &sIv[sr][col0];
    const float* r0 = &sI0[sr][col0];
    const float* r1 = &sI1[sr][col0];
    const float* r2 = &sI2[sr][col0];
    float Gv[12], Iv[12], P0[12], P1[12], P2[12];
    #pragma unroll
    for (int q = 0; q < 3; ++q) {
      *(float4*)&Gv[4 * q] = *(const float4*)(rG + 4 * q);
      *(float4*)&Iv[4 * q] = *(const float4*)(rI + 4 * q);
      *(float4*)&P0[4 * q] = *(const float4*)(r0 + 4 * q);
      *(float4*)&P1[4 * q] = *(const float4*)(r1 + 4 * q);
      *(float4*)&P2[4 * q] = *(const float4*)(r2 + 4 * q);
    }
    #pragma unroll
    for (int k = 0; k < 4; ++k) {
      #pragma unroll
      for (int j = k; j < k + 9; ++j) {
        const int xi = j - k;                    // = dxo + 4, compile-time
        const float Fd = fdr[xi];                // exp(8*dist)
        const float th = thv[xi];                // exp(-8*(m-1))
        float g = Gv[j];
        float t = fmaf(g, Fd, 1.0f);             // 1 + e^{-8r} e^{8d}
        float w = __builtin_amdgcn_rcpf(t) * Iv[j];
        w = (g <= th) ? w : 0.0f;                // window mask (r >= m-1)
        wsum[k] += w;
        ac0[k] = fmaf(w, P0[j], ac0[k]);
        ac1[k] = fmaf(w, P1[j], ac1[k]);
        ac2[k] = fmaf(w, P2[j], ac2[k]);
      }
    }
  }

  const int oy = by + ty;
  const int ox = bx + col0;
  float rw[4];
  #pragma unroll
  for (int k = 0; k < 4; ++k) rw[k] = __builtin_amdgcn_rcpf(wsum[k]);

  float* op0 = out + ((b * 3 + 0) * HH + oy) * WW + ox;
  float* op1 = out + ((b * 3 + 1) * HH + oy) * WW + ox;
  float* op2 = out + ((b * 3 + 2) * HH + oy) * WW + ox;
  float4 v0, v1, v2;
  v0.x = ac0[0] * rw[0]; v0.y = ac0[1] * rw[1]; v0.z = ac0[2] * rw[2]; v0.w = ac0[3] * rw[3];
  v1.x = ac1[0] * rw[0]; v1.y = ac1[1] * rw[1]; v1.z = ac1[2] * rw[2]; v1.w = ac1[3] * rw[3];
  v2.x = ac2[0] * rw[0]; v2.y = ac2[1] * rw[1]; v2.z = ac2[2] * rw[2]; v2.w = ac2[3] * rw[3];
  *(float4*)op0 = v0;
  *(float4*)op1 = v1;
  *(float4*)op2 = v2;
}

extern "C" void kernel_launch(void* const* d_in, const int* in_sizes, int n_in,
                              void* d_out, int out_size, void* d_ws, size_t ws_size,
                              hipStream_t stream) {
  const float* img = (const float*)d_in[0];   // (2,3,512,512) f32
  const float* def = (const float*)d_in[1];   // (2,1,512,512) f32
  float* out = (float*)d_out;                 // (2,3,512,512) f32

  dim3 grid(WW / TILE, HH / TILE, NB);
  dim3 block(256);
  hipLaunchKernelGGL(bokeh_gather, grid, block, 0, stream, img, def, out);
}